// Round 18
// baseline (97.806 us; speedup 1.0000x reference)
//
#include <hip/hip_runtime.h>
#include <hip/hip_bf16.h>
#include <math.h>

#define Bb 16
#define Tt 64
#define Ff 64
#define MAXE 2048

typedef __fp16 h2f __attribute__((ext_vector_type(2)));
__device__ __forceinline__ h2f pkh(float a, float b) {
  return __builtin_amdgcn_cvt_pkrtz(a, b);
}

// ---------------- kprep: block 0 = CSR build; block 1 = weight tables -------
__global__ __launch_bounds__(256) void kprep(
    const int* __restrict__ src, const int* __restrict__ dst, int E,
    const float* __restrict__ W_enc, const float* __restrict__ b_enc,
    const float* __restrict__ W_gat, const float* __restrict__ attn_l,
    const float* __restrict__ attn_r, const float* __restrict__ b_gat,
    int* __restrict__ off, int* __restrict__ csr,
    float* __restrict__ A, float* __restrict__ Bc,
    float* __restrict__ aA, float* __restrict__ aB,
    float* __restrict__ rA, float* __restrict__ rB) {
  __shared__ int s_src[MAXE], s_dst[MAXE];
  __shared__ int cnt[Ff], base[Ff];
  __shared__ __align__(16) float We[64][64], Be[64][64], Wg[64][64];
  __shared__ __align__(16) float As[64][64], Bs[64][64];
  __shared__ float al_s[64], ar_s[64], bg_s[64];
  int t = threadIdx.x;

  if (blockIdx.x == 0) {                       // ---- CSR by dst ----
    for (int e = t; e < E; e += 256) { s_src[e] = src[e]; s_dst[e] = dst[e]; }
    if (t < Ff) cnt[t] = 0;
    __syncthreads();
    for (int e = t; e < E; e += 256) atomicAdd(&cnt[s_dst[e]], 1);
    __syncthreads();
    if (t < 64) {
      // exclusive scan of 64 counts via wave shfl_up (6 steps)
      int c = cnt[t];
      int inc = c;
#pragma unroll
      for (int ofs = 1; ofs < 64; ofs <<= 1) {
        int up = __shfl_up(inc, ofs, 64);
        if (t >= ofs) inc += up;
      }
      int exc = inc - c;
      off[t] = exc;
      base[t] = exc;                 // base[] doubles as running cursor
      if (t == 63) off[64] = inc;
      // ballot-rank stable counting sort: 64 edges/chunk, e-ascending order
      for (int chunk = 0; chunk < E; chunk += 64) {
        int e = chunk + t;
        bool valid = e < E;
        int di = valid ? s_dst[e] : 64;        // sentinel group (bit 6)
        unsigned long long m = ~0ull;
#pragma unroll
        for (int bnum = 0; bnum < 7; ++bnum) {
          unsigned long long bb = __ballot((di >> bnum) & 1);
          m &= ((di >> bnum) & 1) ? bb : ~bb;
        }
        unsigned long long below = m & ((1ull << t) - 1ull);
        int rank = __popcll(below);
        if (valid) {
          int slot = base[di] + rank;
          csr[slot] = s_src[e];
          if (below == 0ull) base[di] += __popcll(m);  // group leader advances
        }
      }
    }
    return;
  }

  // ---- tables: A = We@Wg, Bc = Be@Wg (+b_gat), attn scalar tables ----
  for (int i = t; i < 1024; i += 256) {
    ((float4*)We)[i] = ((const float4*)W_enc)[i];
    ((float4*)Be)[i] = ((const float4*)b_enc)[i];
    ((float4*)Wg)[i] = ((const float4*)W_gat)[i];
  }
  if (t < 64) { al_s[t] = attn_l[t]; ar_s[t] = attn_r[t]; bg_s[t] = b_gat[t]; }
  __syncthreads();
  int n = t >> 2, q = t & 3;
  float accA[16], accB[16];
#pragma unroll
  for (int j = 0; j < 16; ++j) { accA[j] = 0.f; accB[j] = 0.f; }
  for (int k = 0; k < 64; ++k) {
    float we = We[n][k], be = Be[n][k];
#pragma unroll
    for (int c = 0; c < 4; ++c) {
      float4 wg = *(const float4*)&Wg[k][q * 16 + c * 4];
      accA[c*4+0] = fmaf(we, wg.x, accA[c*4+0]); accB[c*4+0] = fmaf(be, wg.x, accB[c*4+0]);
      accA[c*4+1] = fmaf(we, wg.y, accA[c*4+1]); accB[c*4+1] = fmaf(be, wg.y, accB[c*4+1]);
      accA[c*4+2] = fmaf(we, wg.z, accA[c*4+2]); accB[c*4+2] = fmaf(be, wg.z, accB[c*4+2]);
      accA[c*4+3] = fmaf(we, wg.w, accA[c*4+3]); accB[c*4+3] = fmaf(be, wg.w, accB[c*4+3]);
    }
  }
#pragma unroll
  for (int c = 0; c < 4; ++c) {
    float4 va, vb, vbg;
    va.x = accA[c*4+0]; va.y = accA[c*4+1]; va.z = accA[c*4+2]; va.w = accA[c*4+3];
    vb.x = accB[c*4+0]; vb.y = accB[c*4+1]; vb.z = accB[c*4+2]; vb.w = accB[c*4+3];
    vbg.x = vb.x + bg_s[q*16+c*4+0]; vbg.y = vb.y + bg_s[q*16+c*4+1];
    vbg.z = vb.z + bg_s[q*16+c*4+2]; vbg.w = vb.w + bg_s[q*16+c*4+3];
    *(float4*)&As[n][q*16 + c*4] = va;
    *(float4*)&Bs[n][q*16 + c*4] = vb;       // unfolded (attn tables)
    *(float4*)&A[n*64 + q*16 + c*4] = va;
    *(float4*)&Bc[n*64 + q*16 + c*4] = vbg;  // folded (+b_gat; sum(alpha)=1 => exact)
  }
  __syncthreads();
  float sa = 0.f, sb = 0.f, sra = 0.f, srb = 0.f;
#pragma unroll
  for (int j = 0; j < 16; ++j) {
    float alv = al_s[q*16 + j], arv = ar_s[q*16 + j];
    float av = As[n][q*16 + j], bv = Bs[n][q*16 + j];
    sa  = fmaf(av, alv, sa);  sb  = fmaf(bv, alv, sb);
    sra = fmaf(av, arv, sra); srb = fmaf(bv, arv, srb);
  }
  aA[t] = sa; aB[t] = sb; rA[t] = sra; rB[t] = srb;
}

// ---------------- k_gat: per (b,t); feat staged in LDS once ----------------
__global__ __launch_bounds__(256) void k_gat(
    const float* __restrict__ hist, const float* __restrict__ Ag,
    const float* __restrict__ Bg, const float* __restrict__ aAg,
    const float* __restrict__ aBg, const float* __restrict__ rAg,
    const float* __restrict__ rBg, const int* __restrict__ off,
    const int* __restrict__ csr, int E, float* __restrict__ g_out) {
  __shared__ __align__(16) float feat[64 * 68];   // feat' = x*A + Bc (padded rows)
  __shared__ float x_s[64];
  __shared__ float el_s[64][4], er_s[64][4];
  __shared__ int csr_s[1152];
  __shared__ int off_s[Ff + 1];
  int bt = blockIdx.x, t = threadIdx.x;
  if (t < 64) x_s[t] = hist[bt * 64 + t];
  if (t < Ff + 1) off_s[t] = off[t];
  for (int e = t; e < E; e += 256) csr_s[e] = csr[e];
  __syncthreads();

  // ---- stage feat: thread (s, q) -> feat[s][q*16..+15]; coalesced A/Bc ----
  int s0 = t >> 2, q = t & 3;
  {
    float xs = x_s[s0];
    const float4* Ar = (const float4*)(Ag + (s0 << 6) + (q << 4));
    const float4* Br = (const float4*)(Bg + (s0 << 6) + (q << 4));
#pragma unroll
    for (int c = 0; c < 4; ++c) {
      float4 a4 = Ar[c], b4 = Br[c];
      float4 o;
      o.x = fmaf(xs, a4.x, b4.x); o.y = fmaf(xs, a4.y, b4.y);
      o.z = fmaf(xs, a4.z, b4.z); o.w = fmaf(xs, a4.w, b4.w);
      *(float4*)&feat[s0 * 68 + (q << 4) + (c << 2)] = o;
    }
    el_s[s0][q] = fmaf(xs, aAg[t], aBg[t]);
    er_s[s0][q] = fmaf(xs, rAg[t], rBg[t]);
  }
  __syncthreads();

  // ---- edge phase: thread (d, hd); feat from LDS ----
  int d = s0, hd = q;
  int o0 = off_s[d], o1 = off_s[d + 1];
  float erd = er_s[d][hd];
  float den = 0.f;
  float acc[16];
#pragma unroll
  for (int j = 0; j < 16; ++j) acc[j] = 0.f;
  for (int e = o0; e < o1; ++e) {
    int s = csr_s[e];
    float ee = el_s[s][hd] + erd;
    ee = fmaxf(ee, 0.2f * ee);
    float p = __expf(ee);               // no max-shift: |e| bounded, exact alpha
    den += p;
    const float* fr = &feat[s * 68 + (hd << 4)];
#pragma unroll
    for (int c = 0; c < 4; ++c) {
      float4 fv = *(const float4*)&fr[c << 2];
      acc[c*4+0] = fmaf(p, fv.x, acc[c*4+0]);
      acc[c*4+1] = fmaf(p, fv.y, acc[c*4+1]);
      acc[c*4+2] = fmaf(p, fv.z, acc[c*4+2]);
      acc[c*4+3] = fmaf(p, fv.w, acc[c*4+3]);
    }
  }
  float inv = __builtin_amdgcn_rcpf(den);
  float* gp = g_out + (size_t)bt * 4096 + (d << 6) + (hd << 4);
#pragma unroll
  for (int c = 0; c < 4; ++c) {
    float4 o;
    o.x = acc[c*4+0] * inv; o.y = acc[c*4+1] * inv;
    o.z = acc[c*4+2] * inv; o.w = acc[c*4+3] * inv;
    *(float4*)&gp[c << 2] = o;
  }
}

// ---- k_gru: per (f, 2 batches); paired chains for ILP; f16-dot2 matvecs ----
__device__ __forceinline__ float qsum(float v) {
  v += __int_as_float(__builtin_amdgcn_mov_dpp(__float_as_int(v), 0xB1, 0xF, 0xF, true));
  v += __int_as_float(__builtin_amdgcn_mov_dpp(__float_as_int(v), 0x4E, 0xF, 0xF, true));
  return v;
}

__global__ __launch_bounds__(256, 3) void k_gru(
    const float* __restrict__ W_ih, const float* __restrict__ W_hh,
    const float* __restrict__ b_ih, const float* __restrict__ b_hh,
    const float* __restrict__ W_dec, const float* __restrict__ b_dec,
    float* __restrict__ hid, float* __restrict__ ans) {
  __shared__ __align__(16) h2f g16[2][16][32];       // 2 batches' g, f16 (4 KB)
  __shared__ __align__(16) float4 xw4[2][16 * 64];   // [bat][ts*64+row] (32 KB)
  __shared__ __align__(16) __fp16 h16[2][2][64];     // [bat][buf][row] (512 B)
  __shared__ __align__(16) float hbuf[2][2][8][64];  // [bat][gsel][ts][row] (8 KB)
  int blk = blockIdx.x;
  int f = blk & 63, bg = blk >> 6;                   // bg 0..7
  int bA = bg << 1, bB = bA + 1;
  int t = threadIdx.x;
  int row = t >> 2, kg = t & 3;

  const float* Wi = W_ih + f * 12288 + (kg << 4);
  const float* Wh = W_hh + f * 12288 + (kg << 4);
  h2f wi0[8], wi1[8], wi2[8], wh0[8], wh1[8], wh2[8];
#pragma unroll
  for (int c = 0; c < 4; ++c) {
    float4 v;
    v = *(const float4*)(Wi + (row << 6)         + (c << 2));
    wi0[c*2] = pkh(v.x, v.y); wi0[c*2+1] = pkh(v.z, v.w);
    v = *(const float4*)(Wi + ((64 + row) << 6)  + (c << 2));
    wi1[c*2] = pkh(v.x, v.y); wi1[c*2+1] = pkh(v.z, v.w);
    v = *(const float4*)(Wi + ((128 + row) << 6) + (c << 2));
    wi2[c*2] = pkh(v.x, v.y); wi2[c*2+1] = pkh(v.z, v.w);
    v = *(const float4*)(Wh + (row << 6)         + (c << 2));
    wh0[c*2] = pkh(v.x, v.y); wh0[c*2+1] = pkh(v.z, v.w);
    v = *(const float4*)(Wh + ((64 + row) << 6)  + (c << 2));
    wh1[c*2] = pkh(v.x, v.y); wh1[c*2+1] = pkh(v.z, v.w);
    v = *(const float4*)(Wh + ((128 + row) << 6) + (c << 2));
    wh2[c*2] = pkh(v.x, v.y); wh2[c*2+1] = pkh(v.z, v.w);
  }
  float bR  = b_ih[f*192 + row]       + b_hh[f*192 + row];
  float bZ  = b_ih[f*192 + 64 + row]  + b_hh[f*192 + 64 + row];
  float bXN = b_ih[f*192 + 128 + row];
  float bHN = b_hh[f*192 + 128 + row];
  int j2 = t & 31;
  float wd0 = W_dec[(f << 6) + j2], wd1 = W_dec[(f << 6) + 32 + j2];
  float bdec = b_dec[f];
  size_t baseA = (size_t)bA * 262144 + (f << 6);     // hid[b][ts][f][:]
  size_t baseB = (size_t)bB * 262144 + (f << 6);
  float hregA = 0.f, hregB = 0.f;
  if (t < 64) {
    h16[0][0][t] = (__fp16)0.f; h16[0][1][t] = (__fp16)0.f;
    h16[1][0][t] = (__fp16)0.f; h16[1][1][t] = (__fp16)0.f;
  }
  __syncthreads();

#pragma unroll 1
  for (int G = 0; G < 4; ++G) {
    // ---- stage both batches' g as f16 (own columns, in-place safe) ----
#pragma unroll
    for (int r = 0; r < 2; ++r) {
      int idx = r * 256 + t;
      int bb = idx >> 8, rem = idx & 255;
      int i = rem >> 4, ch = rem & 15;
      size_t base = bb ? baseB : baseA;
      float4 v = *(const float4*)&hid[base + (size_t)((G << 4) + i) * 4096 + (ch << 2)];
      g16[bb][i][(ch << 1)]     = pkh(v.x, v.y);
      g16[bb][i][(ch << 1) + 1] = pkh(v.z, v.w);
    }
    __syncthreads();

    // ---- phase A: xw for both batches; g-rows read once per ts ----
#pragma unroll
    for (int ts = 0; ts < 16; ++ts) {
      const h2f* gpA = &g16[0][ts][kg << 3];
      const h2f* gpB = &g16[1][ts][kg << 3];
      h2f gvA[8], gvB[8];
#pragma unroll
      for (int j = 0; j < 8; ++j) { gvA[j] = gpA[j]; gvB[j] = gpB[j]; }
      float a0 = 0.f, a1 = 0.f, a2 = 0.f, b0 = 0.f, b1 = 0.f, b2 = 0.f;
#pragma unroll
      for (int j = 0; j < 8; ++j) {
        a0 = __builtin_amdgcn_fdot2(gvA[j], wi0[j], a0, false);
        b0 = __builtin_amdgcn_fdot2(gvB[j], wi0[j], b0, false);
        a1 = __builtin_amdgcn_fdot2(gvA[j], wi1[j], a1, false);
        b1 = __builtin_amdgcn_fdot2(gvB[j], wi1[j], b1, false);
        a2 = __builtin_amdgcn_fdot2(gvA[j], wi2[j], a2, false);
        b2 = __builtin_amdgcn_fdot2(gvB[j], wi2[j], b2, false);
      }
      a0 = qsum(a0); b0 = qsum(b0); a1 = qsum(a1);
      b1 = qsum(b1); a2 = qsum(a2); b2 = qsum(b2);
      if (kg == 0) {                   // wave-private rows: no barrier needed
        float4 oa; oa.x = a0; oa.y = a1; oa.z = a2; oa.w = 0.f;
        float4 ob; ob.x = b0; ob.y = b1; ob.z = b2; ob.w = 0.f;
        xw4[0][(ts << 6) + row] = oa;
        xw4[1][(ts << 6) + row] = ob;
      }
    }

    // ---- 16 serial GRU steps, two independent chains interleaved ----
#pragma unroll
    for (int st = 0; st < 16; ++st) {
      const int cur = st & 1;
      float4 xgA = xw4[0][(st << 6) + row];
      float4 xgB = xw4[1][(st << 6) + row];
      const h2f* hpA = (const h2f*)&h16[0][cur][kg << 4];
      const h2f* hpB = (const h2f*)&h16[1][cur][kg << 4];
      h2f hvA[8], hvB[8];
#pragma unroll
      for (int j = 0; j < 8; ++j) { hvA[j] = hpA[j]; hvB[j] = hpB[j]; }
      float prA = 0.f, pzA = 0.f, pnA = 0.f;
      float prB = 0.f, pzB = 0.f, pnB = 0.f;
#pragma unroll
      for (int j = 0; j < 8; ++j) {
        prA = __builtin_amdgcn_fdot2(hvA[j], wh0[j], prA, false);
        prB = __builtin_amdgcn_fdot2(hvB[j], wh0[j], prB, false);
        pzA = __builtin_amdgcn_fdot2(hvA[j], wh1[j], pzA, false);
        pzB = __builtin_amdgcn_fdot2(hvB[j], wh1[j], pzB, false);
        pnA = __builtin_amdgcn_fdot2(hvA[j], wh2[j], pnA, false);
        pnB = __builtin_amdgcn_fdot2(hvB[j], wh2[j], pnB, false);
      }
      prA = qsum(prA); prB = qsum(prB); pzA = qsum(pzA);
      pzB = qsum(pzB); pnA = qsum(pnA); pnB = qsum(pnB);
      float rrA = __builtin_amdgcn_rcpf(1.f + __expf(-(prA + xgA.x + bR)));
      float rrB = __builtin_amdgcn_rcpf(1.f + __expf(-(prB + xgB.x + bR)));
      float zzA = __builtin_amdgcn_rcpf(1.f + __expf(-(pzA + xgA.y + bZ)));
      float zzB = __builtin_amdgcn_rcpf(1.f + __expf(-(pzB + xgB.y + bZ)));
      float preA = fmaf(rrA, pnA + bHN, xgA.z + bXN);
      float preB = fmaf(rrB, pnB + bHN, xgB.z + bXN);
      float nnA = 1.f - 2.f * __builtin_amdgcn_rcpf(1.f + __expf(2.f * preA));
      float nnB = 1.f - 2.f * __builtin_amdgcn_rcpf(1.f + __expf(2.f * preB));
      float hnA = fmaf(zzA, hregA - nnA, nnA);
      float hnB = fmaf(zzB, hregB - nnB, nnB);
      hregA = hnA; hregB = hnB;
      if (kg == 0) {
        h16[0][cur ^ 1][row] = (__fp16)hnA;
        h16[1][cur ^ 1][row] = (__fp16)hnB;
      }
      if (kg == 1) {
        hbuf[0][(st >> 3) & 1][st & 7][row] = hnA;
        hbuf[1][(st >> 3) & 1][st & 7][row] = hnB;
      }
      __syncthreads();
      if ((st & 7) == 7) {                  // flush 8 h-rows + fused decode
        const int gsel = (st >> 3) & 1;
        int ts0 = (G << 4) + st - 7;
        {
          int half = t >> 7, tt = t & 127;
          int i = tt >> 4, j = tt & 15;
          float4 hv4 = *(const float4*)&hbuf[half][gsel][i][j << 2];
          size_t base = half ? baseB : baseA;
          *(float4*)&hid[base + (size_t)(ts0 + i) * 4096 + (j << 2)] = hv4;
        }
        int i2 = t >> 5;
        float pa = hbuf[0][gsel][i2][j2] * wd0 + hbuf[0][gsel][i2][j2 + 32] * wd1;
        float pb = hbuf[1][gsel][i2][j2] * wd0 + hbuf[1][gsel][i2][j2 + 32] * wd1;
        pa += __shfl_xor(pa, 1);  pb += __shfl_xor(pb, 1);
        pa += __shfl_xor(pa, 2);  pb += __shfl_xor(pb, 2);
        pa += __shfl_xor(pa, 4);  pb += __shfl_xor(pb, 4);
        pa += __shfl_xor(pa, 8);  pb += __shfl_xor(pb, 8);
        pa += __shfl_xor(pa, 16); pb += __shfl_xor(pb, 16);
        if (j2 == 0) {
          ans[((bA << 6) + ts0 + i2) * 64 + f] = pa + bdec;
          ans[((bB << 6) + ts0 + i2) * 64 + f] = pb + bdec;
        }
      }
    }
  }
}

extern "C" void kernel_launch(void* const* d_in, const int* in_sizes, int n_in,
                              void* d_out, int out_size, void* d_ws, size_t ws_size,
                              hipStream_t stream) {
  const float* hist   = (const float*)d_in[0];
  const int* src      = (const int*)d_in[1];
  const int* dst      = (const int*)d_in[2];
  const float* W_enc  = (const float*)d_in[3];
  const float* b_enc  = (const float*)d_in[4];
  const float* W_gat  = (const float*)d_in[5];
  const float* attn_l = (const float*)d_in[6];
  const float* attn_r = (const float*)d_in[7];
  const float* b_gat  = (const float*)d_in[8];
  const float* W_ih   = (const float*)d_in[9];
  const float* W_hh   = (const float*)d_in[10];
  const float* b_ih   = (const float*)d_in[11];
  const float* b_hh   = (const float*)d_in[12];
  const float* W_dec  = (const float*)d_in[13];
  const float* b_dec  = (const float*)d_in[14];
  int E = in_sizes[1];

  float* ans = (float*)d_out;
  float* hid = (float*)d_out + Bb * Tt * Ff;   // [B,T,F,H]; holds g then h

  int* off   = (int*)d_ws;                     // 65 used (reserve 256)
  int* csr   = off + 256;                      // E used (reserve 2048)
  float* A   = (float*)(csr + 2048);           // 4096
  float* Bc  = A + 4096;                       // 4096 (b_gat folded)
  float* aA  = Bc + 4096;                      // 256
  float* aB  = aA + 256;
  float* rA  = aB + 256;
  float* rB  = rA + 256;

  hipLaunchKernelGGL(kprep, dim3(2), dim3(256), 0, stream,
                     src, dst, E, W_enc, b_enc, W_gat, attn_l, attn_r, b_gat,
                     off, csr, A, Bc, aA, aB, rA, rB);
  hipLaunchKernelGGL(k_gat, dim3(Bb * Tt), dim3(256), 0, stream,
                     hist, A, Bc, aA, aB, rA, rB, off, csr, E, hid);
  hipLaunchKernelGGL(k_gru, dim3(Ff * Bb / 2), dim3(256), 0, stream,
                     W_ih, W_hh, b_ih, b_hh, W_dec, b_dec, hid, ans);
}

// Round 19
// 94.465 us; speedup vs baseline: 1.0354x; 1.0354x over previous
//
#include <hip/hip_runtime.h>
#include <hip/hip_bf16.h>
#include <math.h>

#define Bb 16
#define Tt 64
#define Ff 64
#define MAXE 2048

typedef __fp16 h2f __attribute__((ext_vector_type(2)));
__device__ __forceinline__ h2f pkh(float a, float b) {
  return __builtin_amdgcn_cvt_pkrtz(a, b);
}

// ---------------- kprep: block 0 = CSR build; block 1 = weight tables -------
__global__ __launch_bounds__(256) void kprep(
    const int* __restrict__ src, const int* __restrict__ dst, int E,
    const float* __restrict__ W_enc, const float* __restrict__ b_enc,
    const float* __restrict__ W_gat, const float* __restrict__ attn_l,
    const float* __restrict__ attn_r, const float* __restrict__ b_gat,
    int* __restrict__ off, int* __restrict__ csr,
    float* __restrict__ A, float* __restrict__ Bc,
    float* __restrict__ aA, float* __restrict__ aB,
    float* __restrict__ rA, float* __restrict__ rB) {
  __shared__ int s_src[MAXE], s_dst[MAXE];
  __shared__ int cnt[Ff], base[Ff];
  __shared__ __align__(16) float We[64][64], Be[64][64], Wg[64][64];
  __shared__ __align__(16) float As[64][64], Bs[64][64];
  __shared__ float al_s[64], ar_s[64], bg_s[64];
  int t = threadIdx.x;

  if (blockIdx.x == 0) {                       // ---- CSR by dst ----
    for (int e = t; e < E; e += 256) { s_src[e] = src[e]; s_dst[e] = dst[e]; }
    if (t < Ff) cnt[t] = 0;
    __syncthreads();
    for (int e = t; e < E; e += 256) atomicAdd(&cnt[s_dst[e]], 1);
    __syncthreads();
    if (t < 64) {
      // exclusive scan of 64 counts via wave shfl_up (6 steps)
      int c = cnt[t];
      int inc = c;
#pragma unroll
      for (int ofs = 1; ofs < 64; ofs <<= 1) {
        int up = __shfl_up(inc, ofs, 64);
        if (t >= ofs) inc += up;
      }
      int exc = inc - c;
      off[t] = exc;
      base[t] = exc;                 // base[] doubles as running cursor
      if (t == 63) off[64] = inc;
      // ballot-rank stable counting sort: 64 edges/chunk, e-ascending order
      for (int chunk = 0; chunk < E; chunk += 64) {
        int e = chunk + t;
        bool valid = e < E;
        int di = valid ? s_dst[e] : 64;        // sentinel group (bit 6)
        unsigned long long m = ~0ull;
#pragma unroll
        for (int bnum = 0; bnum < 7; ++bnum) {
          unsigned long long bb = __ballot((di >> bnum) & 1);
          m &= ((di >> bnum) & 1) ? bb : ~bb;
        }
        unsigned long long below = m & ((1ull << t) - 1ull);
        int rank = __popcll(below);
        if (valid) {
          int slot = base[di] + rank;
          csr[slot] = s_src[e];
          if (below == 0ull) base[di] += __popcll(m);  // group leader advances
        }
      }
    }
    return;
  }

  // ---- tables: A = We@Wg, Bc = Be@Wg (+b_gat), attn scalar tables ----
  for (int i = t; i < 1024; i += 256) {
    ((float4*)We)[i] = ((const float4*)W_enc)[i];
    ((float4*)Be)[i] = ((const float4*)b_enc)[i];
    ((float4*)Wg)[i] = ((const float4*)W_gat)[i];
  }
  if (t < 64) { al_s[t] = attn_l[t]; ar_s[t] = attn_r[t]; bg_s[t] = b_gat[t]; }
  __syncthreads();
  int n = t >> 2, q = t & 3;
  float accA[16], accB[16];
#pragma unroll
  for (int j = 0; j < 16; ++j) { accA[j] = 0.f; accB[j] = 0.f; }
  for (int k = 0; k < 64; ++k) {
    float we = We[n][k], be = Be[n][k];
#pragma unroll
    for (int c = 0; c < 4; ++c) {
      float4 wg = *(const float4*)&Wg[k][q * 16 + c * 4];
      accA[c*4+0] = fmaf(we, wg.x, accA[c*4+0]); accB[c*4+0] = fmaf(be, wg.x, accB[c*4+0]);
      accA[c*4+1] = fmaf(we, wg.y, accA[c*4+1]); accB[c*4+1] = fmaf(be, wg.y, accB[c*4+1]);
      accA[c*4+2] = fmaf(we, wg.z, accA[c*4+2]); accB[c*4+2] = fmaf(be, wg.z, accB[c*4+2]);
      accA[c*4+3] = fmaf(we, wg.w, accA[c*4+3]); accB[c*4+3] = fmaf(be, wg.w, accB[c*4+3]);
    }
  }
#pragma unroll
  for (int c = 0; c < 4; ++c) {
    float4 va, vb, vbg;
    va.x = accA[c*4+0]; va.y = accA[c*4+1]; va.z = accA[c*4+2]; va.w = accA[c*4+3];
    vb.x = accB[c*4+0]; vb.y = accB[c*4+1]; vb.z = accB[c*4+2]; vb.w = accB[c*4+3];
    vbg.x = vb.x + bg_s[q*16+c*4+0]; vbg.y = vb.y + bg_s[q*16+c*4+1];
    vbg.z = vb.z + bg_s[q*16+c*4+2]; vbg.w = vb.w + bg_s[q*16+c*4+3];
    *(float4*)&As[n][q*16 + c*4] = va;
    *(float4*)&Bs[n][q*16 + c*4] = vb;       // unfolded (attn tables)
    *(float4*)&A[n*64 + q*16 + c*4] = va;
    *(float4*)&Bc[n*64 + q*16 + c*4] = vbg;  // folded (+b_gat; sum(alpha)=1 => exact)
  }
  __syncthreads();
  float sa = 0.f, sb = 0.f, sra = 0.f, srb = 0.f;
#pragma unroll
  for (int j = 0; j < 16; ++j) {
    float alv = al_s[q*16 + j], arv = ar_s[q*16 + j];
    float av = As[n][q*16 + j], bv = Bs[n][q*16 + j];
    sa  = fmaf(av, alv, sa);  sb  = fmaf(bv, alv, sb);
    sra = fmaf(av, arv, sra); srb = fmaf(bv, arv, srb);
  }
  aA[t] = sa; aB[t] = sb; rA[t] = sra; rB[t] = srb;
}

// ---------------- k_gat: per (b,t); feat staged in LDS once ----------------
__global__ __launch_bounds__(256) void k_gat(
    const float* __restrict__ hist, const float* __restrict__ Ag,
    const float* __restrict__ Bg, const float* __restrict__ aAg,
    const float* __restrict__ aBg, const float* __restrict__ rAg,
    const float* __restrict__ rBg, const int* __restrict__ off,
    const int* __restrict__ csr, int E, float* __restrict__ g_out) {
  __shared__ __align__(16) float feat[64 * 68];   // feat' = x*A + Bc (padded rows)
  __shared__ float x_s[64];
  __shared__ float el_s[64][4], er_s[64][4];
  __shared__ int csr_s[1152];
  __shared__ int off_s[Ff + 1];
  int bt = blockIdx.x, t = threadIdx.x;
  if (t < 64) x_s[t] = hist[bt * 64 + t];
  if (t < Ff + 1) off_s[t] = off[t];
  for (int e = t; e < E; e += 256) csr_s[e] = csr[e];
  __syncthreads();

  // ---- stage feat: thread (s, q) -> feat[s][q*16..+15]; coalesced A/Bc ----
  int s0 = t >> 2, q = t & 3;
  {
    float xs = x_s[s0];
    const float4* Ar = (const float4*)(Ag + (s0 << 6) + (q << 4));
    const float4* Br = (const float4*)(Bg + (s0 << 6) + (q << 4));
#pragma unroll
    for (int c = 0; c < 4; ++c) {
      float4 a4 = Ar[c], b4 = Br[c];
      float4 o;
      o.x = fmaf(xs, a4.x, b4.x); o.y = fmaf(xs, a4.y, b4.y);
      o.z = fmaf(xs, a4.z, b4.z); o.w = fmaf(xs, a4.w, b4.w);
      *(float4*)&feat[s0 * 68 + (q << 4) + (c << 2)] = o;
    }
    el_s[s0][q] = fmaf(xs, aAg[t], aBg[t]);
    er_s[s0][q] = fmaf(xs, rAg[t], rBg[t]);
  }
  __syncthreads();

  // ---- edge phase: thread (d, hd); feat from LDS ----
  int d = s0, hd = q;
  int o0 = off_s[d], o1 = off_s[d + 1];
  float erd = er_s[d][hd];
  float den = 0.f;
  float acc[16];
#pragma unroll
  for (int j = 0; j < 16; ++j) acc[j] = 0.f;
  for (int e = o0; e < o1; ++e) {
    int s = csr_s[e];
    float ee = el_s[s][hd] + erd;
    ee = fmaxf(ee, 0.2f * ee);
    float p = __expf(ee);               // no max-shift: |e| bounded, exact alpha
    den += p;
    const float* fr = &feat[s * 68 + (hd << 4)];
#pragma unroll
    for (int c = 0; c < 4; ++c) {
      float4 fv = *(const float4*)&fr[c << 2];
      acc[c*4+0] = fmaf(p, fv.x, acc[c*4+0]);
      acc[c*4+1] = fmaf(p, fv.y, acc[c*4+1]);
      acc[c*4+2] = fmaf(p, fv.z, acc[c*4+2]);
      acc[c*4+3] = fmaf(p, fv.w, acc[c*4+3]);
    }
  }
  float inv = __builtin_amdgcn_rcpf(den);
  float* gp = g_out + (size_t)bt * 4096 + (d << 6) + (hd << 4);
#pragma unroll
  for (int c = 0; c < 4; ++c) {
    float4 o;
    o.x = acc[c*4+0] * inv; o.y = acc[c*4+1] * inv;
    o.z = acc[c*4+2] * inv; o.w = acc[c*4+3] * inv;
    *(float4*)&gp[c << 2] = o;
  }
}

// ---- k_gru: per (f,b); f16-dot2 matvecs (fp32 accum), g/h inputs packed ----
__device__ __forceinline__ float qsum(float v) {
  v += __int_as_float(__builtin_amdgcn_mov_dpp(__float_as_int(v), 0xB1, 0xF, 0xF, true));
  v += __int_as_float(__builtin_amdgcn_mov_dpp(__float_as_int(v), 0x4E, 0xF, 0xF, true));
  return v;
}

__global__ __launch_bounds__(256, 4) void k_gru(
    const float* __restrict__ W_ih, const float* __restrict__ W_hh,
    const float* __restrict__ b_ih, const float* __restrict__ b_hh,
    const float* __restrict__ W_dec, const float* __restrict__ b_dec,
    float* __restrict__ hid, float* __restrict__ ans) {
  __shared__ __align__(16) h2f g16[16][32];       // one group's g, f16 pairs (2 KB)
  __shared__ __align__(16) float4 xw4[16 * 64];   // [ts][row] {xr,xz,xn,-} (16 KB)
  __shared__ __align__(16) __fp16 h16[2][64];     // h state, f16 (256 B)
  __shared__ __align__(16) float hbuf[2][8][64];
  int blk = blockIdx.x;
  int f = blk & 63, b = blk >> 6;
  int t = threadIdx.x;
  int row = t >> 2, kg = t & 3;

  const float* Wi = W_ih + f * 12288 + (kg << 4);
  const float* Wh = W_hh + f * 12288 + (kg << 4);
  h2f wi0[8], wi1[8], wi2[8], wh0[8], wh1[8], wh2[8];
#pragma unroll
  for (int c = 0; c < 4; ++c) {
    float4 v;
    v = *(const float4*)(Wi + (row << 6)         + (c << 2));
    wi0[c*2] = pkh(v.x, v.y); wi0[c*2+1] = pkh(v.z, v.w);
    v = *(const float4*)(Wi + ((64 + row) << 6)  + (c << 2));
    wi1[c*2] = pkh(v.x, v.y); wi1[c*2+1] = pkh(v.z, v.w);
    v = *(const float4*)(Wi + ((128 + row) << 6) + (c << 2));
    wi2[c*2] = pkh(v.x, v.y); wi2[c*2+1] = pkh(v.z, v.w);
    v = *(const float4*)(Wh + (row << 6)         + (c << 2));
    wh0[c*2] = pkh(v.x, v.y); wh0[c*2+1] = pkh(v.z, v.w);
    v = *(const float4*)(Wh + ((64 + row) << 6)  + (c << 2));
    wh1[c*2] = pkh(v.x, v.y); wh1[c*2+1] = pkh(v.z, v.w);
    v = *(const float4*)(Wh + ((128 + row) << 6) + (c << 2));
    wh2[c*2] = pkh(v.x, v.y); wh2[c*2+1] = pkh(v.z, v.w);
  }
  float bR  = b_ih[f*192 + row]       + b_hh[f*192 + row];
  float bZ  = b_ih[f*192 + 64 + row]  + b_hh[f*192 + 64 + row];
  float bXN = b_ih[f*192 + 128 + row];
  float bHN = b_hh[f*192 + 128 + row];
  int j2 = t & 31;
  float wd0 = W_dec[(f << 6) + j2], wd1 = W_dec[(f << 6) + 32 + j2];
  float bdec = b_dec[f];
  size_t hidbase = (size_t)b * 262144 + (f << 6);   // hid[b][ts][f][:]
  float hreg = 0.f;
  if (t < 64) { h16[0][t] = (__fp16)0.f; h16[1][t] = (__fp16)0.f; }
  __syncthreads();

#pragma unroll 1
  for (int G = 0; G < 4; ++G) {
    // ---- stage this group's g as f16 pairs (own column, in-place safe) ----
    {
      int i = t >> 4, ch = t & 15;
      float4 v = *(const float4*)&hid[hidbase + (size_t)((G << 4) + i) * 4096 + (ch << 2)];
      g16[i][(ch << 1)]     = pkh(v.x, v.y);
      g16[i][(ch << 1) + 1] = pkh(v.z, v.w);
    }
    __syncthreads();

    // ---- phase A: xw via fdot2 (8 dot2/gate); g-row read once per ts ----
#pragma unroll
    for (int ts = 0; ts < 16; ++ts) {
      const h2f* gp = &g16[ts][kg << 3];
      h2f gv[8];
#pragma unroll
      for (int j = 0; j < 8; ++j) gv[j] = gp[j];
      float p0 = 0.f, p1 = 0.f, p2 = 0.f;
#pragma unroll
      for (int j = 0; j < 8; ++j) {
        p0 = __builtin_amdgcn_fdot2(gv[j], wi0[j], p0, false);
        p1 = __builtin_amdgcn_fdot2(gv[j], wi1[j], p1, false);
        p2 = __builtin_amdgcn_fdot2(gv[j], wi2[j], p2, false);
      }
      p0 = qsum(p0); p1 = qsum(p1); p2 = qsum(p2);
      if (kg == 0) {                   // wave-private rows: no barrier needed
        float4 o; o.x = p0; o.y = p1; o.z = p2; o.w = 0.f;
        xw4[(ts << 6) + row] = o;
      }
    }

    // ---- 16 serial GRU steps (fully unrolled, static indices) ----
#pragma unroll
    for (int st = 0; st < 16; ++st) {
      const int cur = st & 1;
      float4 xg = xw4[(st << 6) + row];
      const h2f* hp = (const h2f*)&h16[cur][kg << 4];
      h2f hv[8];
#pragma unroll
      for (int j = 0; j < 8; ++j) hv[j] = hp[j];
      float pr = 0.f, pz = 0.f, pn = 0.f;
#pragma unroll
      for (int j = 0; j < 8; ++j) {
        pr = __builtin_amdgcn_fdot2(hv[j], wh0[j], pr, false);
        pz = __builtin_amdgcn_fdot2(hv[j], wh1[j], pz, false);
        pn = __builtin_amdgcn_fdot2(hv[j], wh2[j], pn, false);
      }
      pr = qsum(pr); pz = qsum(pz); pn = qsum(pn);
      float rr = __builtin_amdgcn_rcpf(1.f + __expf(-(pr + xg.x + bR)));
      float zz = __builtin_amdgcn_rcpf(1.f + __expf(-(pz + xg.y + bZ)));
      float pre = fmaf(rr, pn + bHN, xg.z + bXN);
      float nn = 1.f - 2.f * __builtin_amdgcn_rcpf(1.f + __expf(2.f * pre));
      float hnew = fmaf(zz, hreg - nn, nn);
      hreg = hnew;
      if (kg == 0) h16[cur ^ 1][row] = (__fp16)hnew;
      if (kg == 1) hbuf[(st >> 3) & 1][st & 7][row] = hnew;
      __syncthreads();
      if ((st & 7) == 7) {                  // flush 8 h-rows + fused decode
        const int gsel = (st >> 3) & 1;
        int ts0 = (G << 4) + st - 7;
        if (t < 128) {
          int i = t >> 4, j = t & 15;
          float4 hv4 = *(const float4*)&hbuf[gsel][i][j << 2];
          *(float4*)&hid[hidbase + (size_t)(ts0 + i) * 4096 + (j << 2)] = hv4;
        }
        int i2 = t >> 5;
        float part = hbuf[gsel][i2][j2] * wd0 + hbuf[gsel][i2][j2 + 32] * wd1;
        part += __shfl_xor(part, 1);  part += __shfl_xor(part, 2);
        part += __shfl_xor(part, 4);  part += __shfl_xor(part, 8);
        part += __shfl_xor(part, 16);
        if (j2 == 0) ans[((b << 6) + ts0 + i2) * 64 + f] = part + bdec;
      }
    }
  }
}

extern "C" void kernel_launch(void* const* d_in, const int* in_sizes, int n_in,
                              void* d_out, int out_size, void* d_ws, size_t ws_size,
                              hipStream_t stream) {
  const float* hist   = (const float*)d_in[0];
  const int* src      = (const int*)d_in[1];
  const int* dst      = (const int*)d_in[2];
  const float* W_enc  = (const float*)d_in[3];
  const float* b_enc  = (const float*)d_in[4];
  const float* W_gat  = (const float*)d_in[5];
  const float* attn_l = (const float*)d_in[6];
  const float* attn_r = (const float*)d_in[7];
  const float* b_gat  = (const float*)d_in[8];
  const float* W_ih   = (const float*)d_in[9];
  const float* W_hh   = (const float*)d_in[10];
  const float* b_ih   = (const float*)d_in[11];
  const float* b_hh   = (const float*)d_in[12];
  const float* W_dec  = (const float*)d_in[13];
  const float* b_dec  = (const float*)d_in[14];
  int E = in_sizes[1];

  float* ans = (float*)d_out;
  float* hid = (float*)d_out + Bb * Tt * Ff;   // [B,T,F,H]; holds g then h

  int* off   = (int*)d_ws;                     // 65 used (reserve 256)
  int* csr   = off + 256;                      // E used (reserve 2048)
  float* A   = (float*)(csr + 2048);           // 4096
  float* Bc  = A + 4096;                       // 4096 (b_gat folded)
  float* aA  = Bc + 4096;                      // 256
  float* aB  = aA + 256;
  float* rA  = aB + 256;
  float* rB  = rA + 256;

  hipLaunchKernelGGL(kprep, dim3(2), dim3(256), 0, stream,
                     src, dst, E, W_enc, b_enc, W_gat, attn_l, attn_r, b_gat,
                     off, csr, A, Bc, aA, aB, rA, rB);
  hipLaunchKernelGGL(k_gat, dim3(Bb * Tt), dim3(256), 0, stream,
                     hist, A, Bc, aA, aB, rA, rB, off, csr, E, hid);
  hipLaunchKernelGGL(k_gru, dim3(Ff * Bb), dim3(256), 0, stream,
                     W_ih, W_hh, b_ih, b_hh, W_dec, b_dec, hid, ans);
}

// Round 20
// 93.172 us; speedup vs baseline: 1.0497x; 1.0139x over previous
//
#include <hip/hip_runtime.h>
#include <hip/hip_bf16.h>
#include <math.h>

#define Bb 16
#define Tt 64
#define Ff 64
#define MAXE 2048

typedef __fp16 h2f __attribute__((ext_vector_type(2)));
__device__ __forceinline__ h2f pkh(float a, float b) {
  return __builtin_amdgcn_cvt_pkrtz(a, b);
}

// ---------------- kprep: block 0 = CSR build; block 1 = weight tables -------
__global__ __launch_bounds__(256) void kprep(
    const int* __restrict__ src, const int* __restrict__ dst, int E,
    const float* __restrict__ W_enc, const float* __restrict__ b_enc,
    const float* __restrict__ W_gat, const float* __restrict__ attn_l,
    const float* __restrict__ attn_r, const float* __restrict__ b_gat,
    int* __restrict__ off, int* __restrict__ csr,
    float* __restrict__ A, float* __restrict__ Bc,
    float* __restrict__ aA, float* __restrict__ aB,
    float* __restrict__ rA, float* __restrict__ rB) {
  __shared__ int s_src[MAXE], s_dst[MAXE];
  __shared__ int cnt[Ff], base[Ff];
  __shared__ __align__(16) float We[64][64], Be[64][64], Wg[64][64];
  __shared__ __align__(16) float As[64][64], Bs[64][64];
  __shared__ float al_s[64], ar_s[64], bg_s[64];
  int t = threadIdx.x;

  if (blockIdx.x == 0) {                       // ---- CSR by dst ----
    for (int e = t; e < E; e += 256) { s_src[e] = src[e]; s_dst[e] = dst[e]; }
    if (t < Ff) cnt[t] = 0;
    __syncthreads();
    for (int e = t; e < E; e += 256) atomicAdd(&cnt[s_dst[e]], 1);
    __syncthreads();
    if (t < 64) {
      // exclusive scan of 64 counts via wave shfl_up (6 steps)
      int c = cnt[t];
      int inc = c;
#pragma unroll
      for (int ofs = 1; ofs < 64; ofs <<= 1) {
        int up = __shfl_up(inc, ofs, 64);
        if (t >= ofs) inc += up;
      }
      int exc = inc - c;
      off[t] = exc;
      base[t] = exc;                 // base[] doubles as running cursor
      if (t == 63) off[64] = inc;
      // ballot-rank stable counting sort: 64 edges/chunk, e-ascending order
      for (int chunk = 0; chunk < E; chunk += 64) {
        int e = chunk + t;
        bool valid = e < E;
        int di = valid ? s_dst[e] : 64;        // sentinel group (bit 6)
        unsigned long long m = ~0ull;
#pragma unroll
        for (int bnum = 0; bnum < 7; ++bnum) {
          unsigned long long bb = __ballot((di >> bnum) & 1);
          m &= ((di >> bnum) & 1) ? bb : ~bb;
        }
        unsigned long long below = m & ((1ull << t) - 1ull);
        int rank = __popcll(below);
        if (valid) {
          int slot = base[di] + rank;
          csr[slot] = s_src[e];
          if (below == 0ull) base[di] += __popcll(m);  // group leader advances
        }
      }
    }
    return;
  }

  // ---- tables: A = We@Wg, Bc = Be@Wg (+b_gat), attn scalar tables ----
  for (int i = t; i < 1024; i += 256) {
    ((float4*)We)[i] = ((const float4*)W_enc)[i];
    ((float4*)Be)[i] = ((const float4*)b_enc)[i];
    ((float4*)Wg)[i] = ((const float4*)W_gat)[i];
  }
  if (t < 64) { al_s[t] = attn_l[t]; ar_s[t] = attn_r[t]; bg_s[t] = b_gat[t]; }
  __syncthreads();
  int n = t >> 2, q = t & 3;
  float accA[16], accB[16];
#pragma unroll
  for (int j = 0; j < 16; ++j) { accA[j] = 0.f; accB[j] = 0.f; }
  for (int k = 0; k < 64; ++k) {
    float we = We[n][k], be = Be[n][k];
#pragma unroll
    for (int c = 0; c < 4; ++c) {
      float4 wg = *(const float4*)&Wg[k][q * 16 + c * 4];
      accA[c*4+0] = fmaf(we, wg.x, accA[c*4+0]); accB[c*4+0] = fmaf(be, wg.x, accB[c*4+0]);
      accA[c*4+1] = fmaf(we, wg.y, accA[c*4+1]); accB[c*4+1] = fmaf(be, wg.y, accB[c*4+1]);
      accA[c*4+2] = fmaf(we, wg.z, accA[c*4+2]); accB[c*4+2] = fmaf(be, wg.z, accB[c*4+2]);
      accA[c*4+3] = fmaf(we, wg.w, accA[c*4+3]); accB[c*4+3] = fmaf(be, wg.w, accB[c*4+3]);
    }
  }
#pragma unroll
  for (int c = 0; c < 4; ++c) {
    float4 va, vb, vbg;
    va.x = accA[c*4+0]; va.y = accA[c*4+1]; va.z = accA[c*4+2]; va.w = accA[c*4+3];
    vb.x = accB[c*4+0]; vb.y = accB[c*4+1]; vb.z = accB[c*4+2]; vb.w = accB[c*4+3];
    vbg.x = vb.x + bg_s[q*16+c*4+0]; vbg.y = vb.y + bg_s[q*16+c*4+1];
    vbg.z = vb.z + bg_s[q*16+c*4+2]; vbg.w = vb.w + bg_s[q*16+c*4+3];
    *(float4*)&As[n][q*16 + c*4] = va;
    *(float4*)&Bs[n][q*16 + c*4] = vb;       // unfolded (attn tables)
    *(float4*)&A[n*64 + q*16 + c*4] = va;
    *(float4*)&Bc[n*64 + q*16 + c*4] = vbg;  // folded (+b_gat; sum(alpha)=1 => exact)
  }
  __syncthreads();
  float sa = 0.f, sb = 0.f, sra = 0.f, srb = 0.f;
#pragma unroll
  for (int j = 0; j < 16; ++j) {
    float alv = al_s[q*16 + j], arv = ar_s[q*16 + j];
    float av = As[n][q*16 + j], bv = Bs[n][q*16 + j];
    sa  = fmaf(av, alv, sa);  sb  = fmaf(bv, alv, sb);
    sra = fmaf(av, arv, sra); srb = fmaf(bv, arv, srb);
  }
  aA[t] = sa; aB[t] = sb; rA[t] = sra; rB[t] = srb;
}

// ---------------- k_gat: per (b,t); feat staged in LDS once ----------------
__global__ __launch_bounds__(256) void k_gat(
    const float* __restrict__ hist, const float* __restrict__ Ag,
    const float* __restrict__ Bg, const float* __restrict__ aAg,
    const float* __restrict__ aBg, const float* __restrict__ rAg,
    const float* __restrict__ rBg, const int* __restrict__ off,
    const int* __restrict__ csr, int E, float* __restrict__ g_out) {
  __shared__ __align__(16) float feat[64 * 68];   // feat' = x*A + Bc (padded rows)
  __shared__ float x_s[64];
  __shared__ float el_s[64][4], er_s[64][4];
  __shared__ int csr_s[1152];
  __shared__ int off_s[Ff + 1];
  int bt = blockIdx.x, t = threadIdx.x;
  if (t < 64) x_s[t] = hist[bt * 64 + t];
  if (t < Ff + 1) off_s[t] = off[t];
  for (int e = t; e < E; e += 256) csr_s[e] = csr[e];
  __syncthreads();

  // ---- stage feat: thread (s, q) -> feat[s][q*16..+15]; coalesced A/Bc ----
  int s0 = t >> 2, q = t & 3;
  {
    float xs = x_s[s0];
    const float4* Ar = (const float4*)(Ag + (s0 << 6) + (q << 4));
    const float4* Br = (const float4*)(Bg + (s0 << 6) + (q << 4));
#pragma unroll
    for (int c = 0; c < 4; ++c) {
      float4 a4 = Ar[c], b4 = Br[c];
      float4 o;
      o.x = fmaf(xs, a4.x, b4.x); o.y = fmaf(xs, a4.y, b4.y);
      o.z = fmaf(xs, a4.z, b4.z); o.w = fmaf(xs, a4.w, b4.w);
      *(float4*)&feat[s0 * 68 + (q << 4) + (c << 2)] = o;
    }
    el_s[s0][q] = fmaf(xs, aAg[t], aBg[t]);
    er_s[s0][q] = fmaf(xs, rAg[t], rBg[t]);
  }
  __syncthreads();

  // ---- edge phase: thread (d, hd); feat from LDS ----
  int d = s0, hd = q;
  int o0 = off_s[d], o1 = off_s[d + 1];
  float erd = er_s[d][hd];
  float den = 0.f;
  float acc[16];
#pragma unroll
  for (int j = 0; j < 16; ++j) acc[j] = 0.f;
  for (int e = o0; e < o1; ++e) {
    int s = csr_s[e];
    float ee = el_s[s][hd] + erd;
    ee = fmaxf(ee, 0.2f * ee);
    float p = __expf(ee);               // no max-shift: |e| bounded, exact alpha
    den += p;
    const float* fr = &feat[s * 68 + (hd << 4)];
#pragma unroll
    for (int c = 0; c < 4; ++c) {
      float4 fv = *(const float4*)&fr[c << 2];
      acc[c*4+0] = fmaf(p, fv.x, acc[c*4+0]);
      acc[c*4+1] = fmaf(p, fv.y, acc[c*4+1]);
      acc[c*4+2] = fmaf(p, fv.z, acc[c*4+2]);
      acc[c*4+3] = fmaf(p, fv.w, acc[c*4+3]);
    }
  }
  float inv = __builtin_amdgcn_rcpf(den);
  float* gp = g_out + (size_t)bt * 4096 + (d << 6) + (hd << 4);
#pragma unroll
  for (int c = 0; c < 4; ++c) {
    float4 o;
    o.x = acc[c*4+0] * inv; o.y = acc[c*4+1] * inv;
    o.z = acc[c*4+2] * inv; o.w = acc[c*4+3] * inv;
    *(float4*)&gp[c << 2] = o;
  }
}

// ---- k_gru: ONE WAVE per (f,b) chain; lane = h-row; no barriers, no qsum ---
__global__ __launch_bounds__(64, 1) void k_gru(
    const float* __restrict__ W_ih, const float* __restrict__ W_hh,
    const float* __restrict__ b_ih, const float* __restrict__ b_hh,
    const float* __restrict__ W_dec, const float* __restrict__ b_dec,
    float* __restrict__ hid, float* __restrict__ ans) {
  __shared__ __align__(16) h2f gall[64][32];    // all 64 ts, f16 pairs (8 KB)
  __shared__ __align__(16) __fp16 h16[64];      // h state (128 B), broadcast-read
  int blk = blockIdx.x;
  int f = blk & 63, b = blk >> 6;
  int t = threadIdx.x;                          // lane = h-row

  // ---- all 6 weight rows resident: 192 VGPRs of f16 pairs ----
  const float* WiB = W_ih + f * 12288 + (t << 6);
  const float* WhB = W_hh + f * 12288 + (t << 6);
  h2f wi0[32], wi1[32], wi2[32], wh0[32], wh1[32], wh2[32];
#pragma unroll
  for (int c = 0; c < 16; ++c) {
    float4 v;
    v = *(const float4*)(WiB + (c << 2));
    wi0[c*2] = pkh(v.x, v.y); wi0[c*2+1] = pkh(v.z, v.w);
    v = *(const float4*)(WiB + 4096 + (c << 2));
    wi1[c*2] = pkh(v.x, v.y); wi1[c*2+1] = pkh(v.z, v.w);
    v = *(const float4*)(WiB + 8192 + (c << 2));
    wi2[c*2] = pkh(v.x, v.y); wi2[c*2+1] = pkh(v.z, v.w);
    v = *(const float4*)(WhB + (c << 2));
    wh0[c*2] = pkh(v.x, v.y); wh0[c*2+1] = pkh(v.z, v.w);
    v = *(const float4*)(WhB + 4096 + (c << 2));
    wh1[c*2] = pkh(v.x, v.y); wh1[c*2+1] = pkh(v.z, v.w);
    v = *(const float4*)(WhB + 8192 + (c << 2));
    wh2[c*2] = pkh(v.x, v.y); wh2[c*2+1] = pkh(v.z, v.w);
  }
  float bR  = b_ih[f*192 + t]       + b_hh[f*192 + t];
  float bZ  = b_ih[f*192 + 64 + t]  + b_hh[f*192 + 64 + t];
  float bXN = b_ih[f*192 + 128 + t];
  float bHN = b_hh[f*192 + 128 + t];
  float wd   = W_dec[(f << 6) + t];
  float bdec = b_dec[f];
  size_t base = (size_t)b * 262144 + (f << 6);   // hid[b][ts][f][:]

  // ---- stage ALL 64 g rows as f16 (lane t loads row t; in-place safe) ----
#pragma unroll
  for (int c = 0; c < 16; ++c) {
    float4 v = *(const float4*)&hid[base + (size_t)t * 4096 + (c << 2)];
    gall[t][c*2]     = pkh(v.x, v.y);
    gall[t][c*2+1]   = pkh(v.z, v.w);
  }
  h16[t] = (__fp16)0.f;
  __syncthreads();                               // 1-wave: just a waitcnt

  float hreg = 0.f;
#pragma unroll 4
  for (int ts = 0; ts < 64; ++ts) {
    // broadcast reads: all lanes read the same addresses (conflict-free)
    h2f gv[32], hv[32];
#pragma unroll
    for (int j = 0; j < 8; ++j) {
      *(float4*)&gv[j*4] = *(const float4*)&gall[ts][j*4];
      *(float4*)&hv[j*4] = *(const float4*)&h16[j*8];
    }
    float p0 = 0.f, p1 = 0.f, p2 = 0.f, q0 = 0.f, q1 = 0.f, q2 = 0.f;
#pragma unroll
    for (int j = 0; j < 32; ++j) {
      p0 = __builtin_amdgcn_fdot2(gv[j], wi0[j], p0, false);
      q0 = __builtin_amdgcn_fdot2(hv[j], wh0[j], q0, false);
      p1 = __builtin_amdgcn_fdot2(gv[j], wi1[j], p1, false);
      q1 = __builtin_amdgcn_fdot2(hv[j], wh1[j], q1, false);
      p2 = __builtin_amdgcn_fdot2(gv[j], wi2[j], p2, false);
      q2 = __builtin_amdgcn_fdot2(hv[j], wh2[j], q2, false);
    }
    float rr = __builtin_amdgcn_rcpf(1.f + __expf(-(p0 + q0 + bR)));
    float zz = __builtin_amdgcn_rcpf(1.f + __expf(-(p1 + q1 + bZ)));
    float pre = fmaf(rr, q2 + bHN, p2 + bXN);
    float nn = 1.f - 2.f * __builtin_amdgcn_rcpf(1.f + __expf(2.f * pre));
    float hnew = fmaf(zz, hreg - nn, nn);
    hreg = hnew;
    h16[t] = (__fp16)hnew;                      // next step's hv (in-wave RAW)
    hid[base + (size_t)ts * 4096 + t] = hnew;   // 256B contiguous per wave
    float part = hnew * wd;                     // fused decode, full-wave reduce
    part += __shfl_xor(part, 1);
    part += __shfl_xor(part, 2);
    part += __shfl_xor(part, 4);
    part += __shfl_xor(part, 8);
    part += __shfl_xor(part, 16);
    part += __shfl_xor(part, 32);
    if (t == 0) ans[(((b << 6) + ts) << 6) + f] = part + bdec;
    __syncthreads();                            // 1-wave: waitcnt-only ordering
  }
}

extern "C" void kernel_launch(void* const* d_in, const int* in_sizes, int n_in,
                              void* d_out, int out_size, void* d_ws, size_t ws_size,
                              hipStream_t stream) {
  const float* hist   = (const float*)d_in[0];
  const int* src      = (const int*)d_in[1];
  const int* dst      = (const int*)d_in[2];
  const float* W_enc  = (const float*)d_in[3];
  const float* b_enc  = (const float*)d_in[4];
  const float* W_gat  = (const float*)d_in[5];
  const float* attn_l = (const float*)d_in[6];
  const float* attn_r = (const float*)d_in[7];
  const float* b_gat  = (const float*)d_in[8];
  const float* W_ih   = (const float*)d_in[9];
  const float* W_hh   = (const float*)d_in[10];
  const float* b_ih   = (const float*)d_in[11];
  const float* b_hh   = (const float*)d_in[12];
  const float* W_dec  = (const float*)d_in[13];
  const float* b_dec  = (const float*)d_in[14];
  int E = in_sizes[1];

  float* ans = (float*)d_out;
  float* hid = (float*)d_out + Bb * Tt * Ff;   // [B,T,F,H]; holds g then h

  int* off   = (int*)d_ws;                     // 65 used (reserve 256)
  int* csr   = off + 256;                      // E used (reserve 2048)
  float* A   = (float*)(csr + 2048);           // 4096
  float* Bc  = A + 4096;                       // 4096 (b_gat folded)
  float* aA  = Bc + 4096;                      // 256
  float* aB  = aA + 256;
  float* rA  = aB + 256;
  float* rB  = rA + 256;

  hipLaunchKernelGGL(kprep, dim3(2), dim3(256), 0, stream,
                     src, dst, E, W_enc, b_enc, W_gat, attn_l, attn_r, b_gat,
                     off, csr, A, Bc, aA, aB, rA, rB);
  hipLaunchKernelGGL(k_gat, dim3(Bb * Tt), dim3(256), 0, stream,
                     hist, A, Bc, aA, aB, rA, rB, off, csr, E, hid);
  hipLaunchKernelGGL(k_gru, dim3(Ff * Bb), dim3(64), 0, stream,
                     W_ih, W_hh, b_ih, b_hh, W_dec, b_dec, hid, ans);
}

// Round 21
// 93.150 us; speedup vs baseline: 1.0500x; 1.0002x over previous
//
#include <hip/hip_runtime.h>
#include <hip/hip_bf16.h>
#include <math.h>

#define Bb 16
#define Tt 64
#define Ff 64
#define MAXE 2048

typedef __fp16 h2f __attribute__((ext_vector_type(2)));
__device__ __forceinline__ h2f pkh(float a, float b) {
  return __builtin_amdgcn_cvt_pkrtz(a, b);
}

// ---------------- kprep: block 0 = CSR build; block 1 = weight tables -------
__global__ __launch_bounds__(256) void kprep(
    const int* __restrict__ src, const int* __restrict__ dst, int E,
    const float* __restrict__ W_enc, const float* __restrict__ b_enc,
    const float* __restrict__ W_gat, const float* __restrict__ attn_l,
    const float* __restrict__ attn_r, const float* __restrict__ b_gat,
    int* __restrict__ off, int* __restrict__ csr,
    float* __restrict__ A, float* __restrict__ Bc,
    float* __restrict__ aA, float* __restrict__ aB,
    float* __restrict__ rA, float* __restrict__ rB) {
  __shared__ int s_src[MAXE], s_dst[MAXE];
  __shared__ int cnt[Ff], base[Ff];
  __shared__ __align__(16) float We[64][64], Be[64][64], Wg[64][64];
  __shared__ __align__(16) float As[64][64], Bs[64][64];
  __shared__ float al_s[64], ar_s[64], bg_s[64];
  int t = threadIdx.x;

  if (blockIdx.x == 0) {                       // ---- CSR by dst ----
    for (int e = t; e < E; e += 256) { s_src[e] = src[e]; s_dst[e] = dst[e]; }
    if (t < Ff) cnt[t] = 0;
    __syncthreads();
    for (int e = t; e < E; e += 256) atomicAdd(&cnt[s_dst[e]], 1);
    __syncthreads();
    if (t < 64) {
      // exclusive scan of 64 counts via wave shfl_up (6 steps)
      int c = cnt[t];
      int inc = c;
#pragma unroll
      for (int ofs = 1; ofs < 64; ofs <<= 1) {
        int up = __shfl_up(inc, ofs, 64);
        if (t >= ofs) inc += up;
      }
      int exc = inc - c;
      off[t] = exc;
      base[t] = exc;                 // base[] doubles as running cursor
      if (t == 63) off[64] = inc;
      // ballot-rank stable counting sort: 64 edges/chunk, e-ascending order
      for (int chunk = 0; chunk < E; chunk += 64) {
        int e = chunk + t;
        bool valid = e < E;
        int di = valid ? s_dst[e] : 64;        // sentinel group (bit 6)
        unsigned long long m = ~0ull;
#pragma unroll
        for (int bnum = 0; bnum < 7; ++bnum) {
          unsigned long long bb = __ballot((di >> bnum) & 1);
          m &= ((di >> bnum) & 1) ? bb : ~bb;
        }
        unsigned long long below = m & ((1ull << t) - 1ull);
        int rank = __popcll(below);
        if (valid) {
          int slot = base[di] + rank;
          csr[slot] = s_src[e];
          if (below == 0ull) base[di] += __popcll(m);  // group leader advances
        }
      }
    }
    return;
  }

  // ---- tables: A = We@Wg, Bc = Be@Wg (+b_gat), attn scalar tables ----
  for (int i = t; i < 1024; i += 256) {
    ((float4*)We)[i] = ((const float4*)W_enc)[i];
    ((float4*)Be)[i] = ((const float4*)b_enc)[i];
    ((float4*)Wg)[i] = ((const float4*)W_gat)[i];
  }
  if (t < 64) { al_s[t] = attn_l[t]; ar_s[t] = attn_r[t]; bg_s[t] = b_gat[t]; }
  __syncthreads();
  int n = t >> 2, q = t & 3;
  float accA[16], accB[16];
#pragma unroll
  for (int j = 0; j < 16; ++j) { accA[j] = 0.f; accB[j] = 0.f; }
  for (int k = 0; k < 64; ++k) {
    float we = We[n][k], be = Be[n][k];
#pragma unroll
    for (int c = 0; c < 4; ++c) {
      float4 wg = *(const float4*)&Wg[k][q * 16 + c * 4];
      accA[c*4+0] = fmaf(we, wg.x, accA[c*4+0]); accB[c*4+0] = fmaf(be, wg.x, accB[c*4+0]);
      accA[c*4+1] = fmaf(we, wg.y, accA[c*4+1]); accB[c*4+1] = fmaf(be, wg.y, accB[c*4+1]);
      accA[c*4+2] = fmaf(we, wg.z, accA[c*4+2]); accB[c*4+2] = fmaf(be, wg.z, accB[c*4+2]);
      accA[c*4+3] = fmaf(we, wg.w, accA[c*4+3]); accB[c*4+3] = fmaf(be, wg.w, accB[c*4+3]);
    }
  }
#pragma unroll
  for (int c = 0; c < 4; ++c) {
    float4 va, vb, vbg;
    va.x = accA[c*4+0]; va.y = accA[c*4+1]; va.z = accA[c*4+2]; va.w = accA[c*4+3];
    vb.x = accB[c*4+0]; vb.y = accB[c*4+1]; vb.z = accB[c*4+2]; vb.w = accB[c*4+3];
    vbg.x = vb.x + bg_s[q*16+c*4+0]; vbg.y = vb.y + bg_s[q*16+c*4+1];
    vbg.z = vb.z + bg_s[q*16+c*4+2]; vbg.w = vb.w + bg_s[q*16+c*4+3];
    *(float4*)&As[n][q*16 + c*4] = va;
    *(float4*)&Bs[n][q*16 + c*4] = vb;       // unfolded (attn tables)
    *(float4*)&A[n*64 + q*16 + c*4] = va;
    *(float4*)&Bc[n*64 + q*16 + c*4] = vbg;  // folded (+b_gat; sum(alpha)=1 => exact)
  }
  __syncthreads();
  float sa = 0.f, sb = 0.f, sra = 0.f, srb = 0.f;
#pragma unroll
  for (int j = 0; j < 16; ++j) {
    float alv = al_s[q*16 + j], arv = ar_s[q*16 + j];
    float av = As[n][q*16 + j], bv = Bs[n][q*16 + j];
    sa  = fmaf(av, alv, sa);  sb  = fmaf(bv, alv, sb);
    sra = fmaf(av, arv, sra); srb = fmaf(bv, arv, srb);
  }
  aA[t] = sa; aB[t] = sb; rA[t] = sra; rB[t] = srb;
}

// ---------------- k_gat: per (b,t); feat staged in LDS once ----------------
__global__ __launch_bounds__(256) void k_gat(
    const float* __restrict__ hist, const float* __restrict__ Ag,
    const float* __restrict__ Bg, const float* __restrict__ aAg,
    const float* __restrict__ aBg, const float* __restrict__ rAg,
    const float* __restrict__ rBg, const int* __restrict__ off,
    const int* __restrict__ csr, int E, float* __restrict__ g_out) {
  __shared__ __align__(16) float feat[64 * 68];   // feat' = x*A + Bc (padded rows)
  __shared__ float x_s[64];
  __shared__ float el_s[64][4], er_s[64][4];
  __shared__ int csr_s[1152];
  __shared__ int off_s[Ff + 1];
  int bt = blockIdx.x, t = threadIdx.x;
  if (t < 64) x_s[t] = hist[bt * 64 + t];
  if (t < Ff + 1) off_s[t] = off[t];
  for (int e = t; e < E; e += 256) csr_s[e] = csr[e];
  __syncthreads();

  // ---- stage feat: thread (s, q) -> feat[s][q*16..+15]; coalesced A/Bc ----
  int s0 = t >> 2, q = t & 3;
  {
    float xs = x_s[s0];
    const float4* Ar = (const float4*)(Ag + (s0 << 6) + (q << 4));
    const float4* Br = (const float4*)(Bg + (s0 << 6) + (q << 4));
#pragma unroll
    for (int c = 0; c < 4; ++c) {
      float4 a4 = Ar[c], b4 = Br[c];
      float4 o;
      o.x = fmaf(xs, a4.x, b4.x); o.y = fmaf(xs, a4.y, b4.y);
      o.z = fmaf(xs, a4.z, b4.z); o.w = fmaf(xs, a4.w, b4.w);
      *(float4*)&feat[s0 * 68 + (q << 4) + (c << 2)] = o;
    }
    el_s[s0][q] = fmaf(xs, aAg[t], aBg[t]);
    er_s[s0][q] = fmaf(xs, rAg[t], rBg[t]);
  }
  __syncthreads();

  // ---- edge phase: thread (d, hd); feat from LDS ----
  int d = s0, hd = q;
  int o0 = off_s[d], o1 = off_s[d + 1];
  float erd = er_s[d][hd];
  float den = 0.f;
  float acc[16];
#pragma unroll
  for (int j = 0; j < 16; ++j) acc[j] = 0.f;
  for (int e = o0; e < o1; ++e) {
    int s = csr_s[e];
    float ee = el_s[s][hd] + erd;
    ee = fmaxf(ee, 0.2f * ee);
    float p = __expf(ee);               // no max-shift: |e| bounded, exact alpha
    den += p;
    const float* fr = &feat[s * 68 + (hd << 4)];
#pragma unroll
    for (int c = 0; c < 4; ++c) {
      float4 fv = *(const float4*)&fr[c << 2];
      acc[c*4+0] = fmaf(p, fv.x, acc[c*4+0]);
      acc[c*4+1] = fmaf(p, fv.y, acc[c*4+1]);
      acc[c*4+2] = fmaf(p, fv.z, acc[c*4+2]);
      acc[c*4+3] = fmaf(p, fv.w, acc[c*4+3]);
    }
  }
  float inv = __builtin_amdgcn_rcpf(den);
  float* gp = g_out + (size_t)bt * 4096 + (d << 6) + (hd << 4);
#pragma unroll
  for (int c = 0; c < 4; ++c) {
    float4 o;
    o.x = acc[c*4+0] * inv; o.y = acc[c*4+1] * inv;
    o.z = acc[c*4+2] * inv; o.w = acc[c*4+3] * inv;
    *(float4*)&gp[c << 2] = o;
  }
}

// ---- k_gru: ONE WAVE per (f,b); weights pinned in VGPRs via asm launder ----
__global__ __launch_bounds__(64, 1) void k_gru(
    const float* __restrict__ W_ih, const float* __restrict__ W_hh,
    const float* __restrict__ b_ih, const float* __restrict__ b_hh,
    const float* __restrict__ W_dec, const float* __restrict__ b_dec,
    float* __restrict__ hid, float* __restrict__ ans) {
  __shared__ __align__(16) h2f gall[64][32];    // all 64 ts, f16 pairs (8 KB)
  __shared__ __align__(16) __fp16 h16[64];      // h state (128 B), broadcast-read
  int blk = blockIdx.x;
  int f = blk & 63, b = blk >> 6;
  int t = threadIdx.x;                          // lane = h-row

  // ---- all 6 weight rows resident: 192 VGPRs of f16 pairs ----
  const float* WiB = W_ih + f * 12288 + (t << 6);
  const float* WhB = W_hh + f * 12288 + (t << 6);
  h2f wi0[32], wi1[32], wi2[32], wh0[32], wh1[32], wh2[32];
#pragma unroll
  for (int c = 0; c < 16; ++c) {
    float4 v;
    v = *(const float4*)(WiB + (c << 2));
    wi0[c*2] = pkh(v.x, v.y); wi0[c*2+1] = pkh(v.z, v.w);
    v = *(const float4*)(WiB + 4096 + (c << 2));
    wi1[c*2] = pkh(v.x, v.y); wi1[c*2+1] = pkh(v.z, v.w);
    v = *(const float4*)(WiB + 8192 + (c << 2));
    wi2[c*2] = pkh(v.x, v.y); wi2[c*2+1] = pkh(v.z, v.w);
    v = *(const float4*)(WhB + (c << 2));
    wh0[c*2] = pkh(v.x, v.y); wh0[c*2+1] = pkh(v.z, v.w);
    v = *(const float4*)(WhB + 4096 + (c << 2));
    wh1[c*2] = pkh(v.x, v.y); wh1[c*2+1] = pkh(v.z, v.w);
    v = *(const float4*)(WhB + 8192 + (c << 2));
    wh2[c*2] = pkh(v.x, v.y); wh2[c*2+1] = pkh(v.z, v.w);
  }
  // pin weights in VGPRs: opaque asm outputs cannot be rematerialized
#pragma unroll
  for (int j = 0; j < 32; ++j) {
    asm volatile("" : "+v"(wi0[j]), "+v"(wi1[j]), "+v"(wi2[j]),
                      "+v"(wh0[j]), "+v"(wh1[j]), "+v"(wh2[j]));
  }
  float bR  = b_ih[f*192 + t]       + b_hh[f*192 + t];
  float bZ  = b_ih[f*192 + 64 + t]  + b_hh[f*192 + 64 + t];
  float bXN = b_ih[f*192 + 128 + t];
  float bHN = b_hh[f*192 + 128 + t];
  float wd   = W_dec[(f << 6) + t];
  float bdec = b_dec[f];
  size_t base = (size_t)b * 262144 + (f << 6);   // hid[b][ts][f][:]

  // ---- stage ALL 64 g rows as f16 (lane t loads row t; in-place safe) ----
#pragma unroll
  for (int c = 0; c < 16; ++c) {
    float4 v = *(const float4*)&hid[base + (size_t)t * 4096 + (c << 2)];
    gall[t][c*2]     = pkh(v.x, v.y);
    gall[t][c*2+1]   = pkh(v.z, v.w);
  }
  h16[t] = (__fp16)0.f;
  __syncthreads();                               // 1-wave: just a waitcnt

  float hreg = 0.f;
#pragma unroll 4
  for (int ts = 0; ts < 64; ++ts) {
    // broadcast reads: all lanes read the same addresses (conflict-free)
    h2f gv[32], hv[32];
#pragma unroll
    for (int j = 0; j < 8; ++j) {
      *(float4*)&gv[j*4] = *(const float4*)&gall[ts][j*4];
      *(float4*)&hv[j*4] = *(const float4*)&h16[j*8];
    }
    float p0 = 0.f, p1 = 0.f, p2 = 0.f, q0 = 0.f, q1 = 0.f, q2 = 0.f;
#pragma unroll
    for (int j = 0; j < 32; ++j) {
      p0 = __builtin_amdgcn_fdot2(gv[j], wi0[j], p0, false);
      q0 = __builtin_amdgcn_fdot2(hv[j], wh0[j], q0, false);
      p1 = __builtin_amdgcn_fdot2(gv[j], wi1[j], p1, false);
      q1 = __builtin_amdgcn_fdot2(hv[j], wh1[j], q1, false);
      p2 = __builtin_amdgcn_fdot2(gv[j], wi2[j], p2, false);
      q2 = __builtin_amdgcn_fdot2(hv[j], wh2[j], q2, false);
    }
    float rr = __builtin_amdgcn_rcpf(1.f + __expf(-(p0 + q0 + bR)));
    float zz = __builtin_amdgcn_rcpf(1.f + __expf(-(p1 + q1 + bZ)));
    float pre = fmaf(rr, q2 + bHN, p2 + bXN);
    float nn = 1.f - 2.f * __builtin_amdgcn_rcpf(1.f + __expf(2.f * pre));
    float hnew = fmaf(zz, hreg - nn, nn);
    hreg = hnew;
    h16[t] = (__fp16)hnew;                      // next step's hv (in-wave RAW)
    hid[base + (size_t)ts * 4096 + t] = hnew;   // 256B contiguous per wave
    float part = hnew * wd;                     // fused decode, full-wave reduce
    part += __shfl_xor(part, 1);
    part += __shfl_xor(part, 2);
    part += __shfl_xor(part, 4);
    part += __shfl_xor(part, 8);
    part += __shfl_xor(part, 16);
    part += __shfl_xor(part, 32);
    if (t == 0) ans[(((b << 6) + ts) << 6) + f] = part + bdec;
    __syncthreads();                            // 1-wave: waitcnt-only ordering
  }
}

extern "C" void kernel_launch(void* const* d_in, const int* in_sizes, int n_in,
                              void* d_out, int out_size, void* d_ws, size_t ws_size,
                              hipStream_t stream) {
  const float* hist   = (const float*)d_in[0];
  const int* src      = (const int*)d_in[1];
  const int* dst      = (const int*)d_in[2];
  const float* W_enc  = (const float*)d_in[3];
  const float* b_enc  = (const float*)d_in[4];
  const float* W_gat  = (const float*)d_in[5];
  const float* attn_l = (const float*)d_in[6];
  const float* attn_r = (const float*)d_in[7];
  const float* b_gat  = (const float*)d_in[8];
  const float* W_ih   = (const float*)d_in[9];
  const float* W_hh   = (const float*)d_in[10];
  const float* b_ih   = (const float*)d_in[11];
  const float* b_hh   = (const float*)d_in[12];
  const float* W_dec  = (const float*)d_in[13];
  const float* b_dec  = (const float*)d_in[14];
  int E = in_sizes[1];

  float* ans = (float*)d_out;
  float* hid = (float*)d_out + Bb * Tt * Ff;   // [B,T,F,H]; holds g then h

  int* off   = (int*)d_ws;                     // 65 used (reserve 256)
  int* csr   = off + 256;                      // E used (reserve 2048)
  float* A   = (float*)(csr + 2048);           // 4096
  float* Bc  = A + 4096;                       // 4096 (b_gat folded)
  float* aA  = Bc + 4096;                      // 256
  float* aB  = aA + 256;
  float* rA  = aB + 256;
  float* rB  = rA + 256;

  hipLaunchKernelGGL(kprep, dim3(2), dim3(256), 0, stream,
                     src, dst, E, W_enc, b_enc, W_gat, attn_l, attn_r, b_gat,
                     off, csr, A, Bc, aA, aB, rA, rB);
  hipLaunchKernelGGL(k_gat, dim3(Bb * Tt), dim3(256), 0, stream,
                     hist, A, Bc, aA, aB, rA, rB, off, csr, E, hid);
  hipLaunchKernelGGL(k_gru, dim3(Ff * Bb), dim3(64), 0, stream,
                     W_ih, W_hh, b_ih, b_hh, W_dec, b_dec, hid, ans);
}